// Round 1
// baseline (441.576 us; speedup 1.0000x reference)
//
#include <hip/hip_runtime.h>

// EMA with bias correction along last axis.
// x: (32, 256, 8192) fp32  ->  out same shape.
// y[t] = 0.99*y[t-1] + 0.01*x[t], y[-1]=0 ; out[t] = y[t] / (1 - 0.99^(t+1))
//
// One 256-thread block per row (8192 rows).
//   stage-in : global_load_lds width-16 DMA, source index pre-swizzled
//              (LDS dest lane-linear as HW requires; LDS holds sw4 layout)
//   scan     : 8 x ds_read_b128 (swizzled addr, 2-way banks = free) +
//              32-elem sequential register scan
//   carry    : Kogge-Stone shuffle scan (constexpr decay powers) +
//              cross-wave combine via 4 floats overlaid on sm4
//   epilogue : bias-correct (rcp only for wave 0 -- exact, corr==1.0f for
//              t>=2048) and store straight to global as per-thread float4s
//              (L2 merges the 128B-strided 16B stores into full lines).

namespace {

constexpr int T = 8192;
constexpr int BLOCK = 256;
constexpr int CHUNK = T / BLOCK;    // 32 elements per thread
constexpr int NWAVE = BLOCK / 64;   // 4
constexpr int V4 = T / 4;           // 2048 float4 slots in LDS
constexpr int VPT = V4 / BLOCK;     // 8 float4 per thread

// XOR swizzle at float4 granularity: slot bits [2:0] ^= bits [5:3].
// Involution; never leaves the slot's 8-slot (128 B) period, so the
// DMA's wave-level 1 KiB destination window is unchanged.
__device__ __forceinline__ int sw4(int v) { return v ^ ((v >> 3) & 7); }

__global__ __launch_bounds__(BLOCK, 5) void ema_kernel(const float* __restrict__ x,
                                                       float* __restrict__ out) {
  __shared__ float4 sm4[V4];   // exactly 32 KiB -> 5 blocks/CU

  const int tid = threadIdx.x;
  const long long base = (long long)blockIdx.x * (long long)T;

  // ---- stage in: coalesced DMA, global source pre-swizzled ----
  const float4* xv = reinterpret_cast<const float4*>(x + base);
#pragma unroll
  for (int k = 0; k < VPT; ++k) {
    const int slot = tid + BLOCK * k;   // lane-linear LDS dest (HW requirement)
    const int g = sw4(slot);            // swizzle applied to the SOURCE
    __builtin_amdgcn_global_load_lds(
        (const __attribute__((address_space(1))) void*)(xv + g),
        (__attribute__((address_space(3))) void*)(sm4 + slot), 16, 0, 0);
  }
  asm volatile("s_waitcnt vmcnt(0)" ::: "memory");
  __syncthreads();

  constexpr float A1 = 0.99f, M = 0.01f;
  constexpr float A2 = A1 * A1;
  constexpr float A4 = A2 * A2;
  constexpr float A8 = A4 * A4;
  constexpr float A16 = A8 * A8;
  constexpr float A32 = A16 * A16;       // decay across one CHUNK
  constexpr float A64 = A32 * A32;
  constexpr float A128 = A64 * A64;
  constexpr float A256 = A128 * A128;
  constexpr float A512 = A256 * A256;
  constexpr float A1024 = A512 * A512;
  constexpr float A2048 = A1024 * A1024; // decay across one wave (64 chunks)

  // ---- per-thread sequential scan of its contiguous chunk ----
  const int vbase = tid * VPT;
  float acc[CHUNK];
  float run = 0.0f;
#pragma unroll
  for (int e4 = 0; e4 < VPT; ++e4) {
    const float4 v = sm4[sw4(vbase + e4)];   // ds_read_b128, conflict-free
    run = fmaf(run, A1, M * v.x); acc[4 * e4 + 0] = run;
    run = fmaf(run, A1, M * v.y); acc[4 * e4 + 1] = run;
    run = fmaf(run, A1, M * v.z); acc[4 * e4 + 2] = run;
    run = fmaf(run, A1, M * v.w); acc[4 * e4 + 3] = run;
  }

  const int lane = tid & 63;
  const int w = tid >> 6;

  // ---- Kogge-Stone inclusive scan of chunk-finals across the wave ----
  float S = run;
  {
    float t;
    t = __shfl_up(S, 1, 64);  if (lane >= 1)  S = fmaf(t, A32,   S);
    t = __shfl_up(S, 2, 64);  if (lane >= 2)  S = fmaf(t, A64,   S);
    t = __shfl_up(S, 4, 64);  if (lane >= 4)  S = fmaf(t, A128,  S);
    t = __shfl_up(S, 8, 64);  if (lane >= 8)  S = fmaf(t, A256,  S);
    t = __shfl_up(S, 16, 64); if (lane >= 16) S = fmaf(t, A512,  S);
    t = __shfl_up(S, 32, 64); if (lane >= 32) S = fmaf(t, A1024, S);
  }
  const float Sprev = __shfl_up(S, 1, 64);

  // ---- cross-wave combine: overlay 4 floats on sm4 (keeps LDS at 32 KiB) ----
  __syncthreads();                         // all scan reads of sm4 done
  float* smW = reinterpret_cast<float*>(sm4);
  if (lane == 63) smW[w] = S;              // wave total W_w
  __syncthreads();

  // Q_w = sum_{v<w} A2048^(w-1-v) * W_v
  float Q = 0.0f;
#pragma unroll
  for (int v = 0; v < NWAVE - 1; ++v) {
    if (v < w) Q = fmaf(Q, A2048, smW[v]);
  }

  // Dlane = A32^lane (exact binary decomposition)
  float Dlane = 1.0f;
  if (lane & 1)  Dlane *= A32;
  if (lane & 2)  Dlane *= A64;
  if (lane & 4)  Dlane *= A128;
  if (lane & 8)  Dlane *= A256;
  if (lane & 16) Dlane *= A512;
  if (lane & 32) Dlane *= A1024;

  // carry = y[cbase - 1]
  const float carry = (lane ? Sprev : 0.0f) + Dlane * Q;

  // ---- epilogue: bias-correct, store per-thread float4s directly ----
  float4* ov = reinterpret_cast<float4*>(out + base);
  float pw = 1.0f;

  if (w == 0) {
    // t < 2048: real correction. Pt = 0.99^(32*tid), tid < 64.
    float Pt = 1.0f;
    if (tid & 1)  Pt *= A32;
    if (tid & 2)  Pt *= A64;
    if (tid & 4)  Pt *= A128;
    if (tid & 8)  Pt *= A256;
    if (tid & 16) Pt *= A512;
    if (tid & 32) Pt *= A1024;
#pragma unroll
    for (int e4 = 0; e4 < VPT; ++e4) {
      float4 o;
      pw *= A1; Pt *= A1;
      o.x = fmaf(carry, pw, acc[4 * e4 + 0]) * __builtin_amdgcn_rcpf(1.0f - Pt);
      pw *= A1; Pt *= A1;
      o.y = fmaf(carry, pw, acc[4 * e4 + 1]) * __builtin_amdgcn_rcpf(1.0f - Pt);
      pw *= A1; Pt *= A1;
      o.z = fmaf(carry, pw, acc[4 * e4 + 2]) * __builtin_amdgcn_rcpf(1.0f - Pt);
      pw *= A1; Pt *= A1;
      o.w = fmaf(carry, pw, acc[4 * e4 + 3]) * __builtin_amdgcn_rcpf(1.0f - Pt);
      ov[vbase + e4] = o;
    }
  } else {
    // t >= 2048: Pt <= 0.99^2049 ~ 1.1e-9 < 2^-25, so 1-Pt == 1.0f and
    // corr == 1.0f exactly -- identical to the rcp path, without the rcp.
#pragma unroll
    for (int e4 = 0; e4 < VPT; ++e4) {
      float4 o;
      pw *= A1; o.x = fmaf(carry, pw, acc[4 * e4 + 0]);
      pw *= A1; o.y = fmaf(carry, pw, acc[4 * e4 + 1]);
      pw *= A1; o.z = fmaf(carry, pw, acc[4 * e4 + 2]);
      pw *= A1; o.w = fmaf(carry, pw, acc[4 * e4 + 3]);
      ov[vbase + e4] = o;
    }
  }
}

}  // namespace

extern "C" void kernel_launch(void* const* d_in, const int* in_sizes, int n_in,
                              void* d_out, int out_size, void* d_ws, size_t ws_size,
                              hipStream_t stream) {
  const float* x = (const float*)d_in[0];
  float* out = (float*)d_out;
  const int rows = in_sizes[0] / T;  // 32*256 = 8192
  ema_kernel<<<dim3(rows), dim3(BLOCK), 0, stream>>>(x, out);
}

// Round 2
// 432.973 us; speedup vs baseline: 1.0199x; 1.0199x over previous
//
#include <hip/hip_runtime.h>

// EMA with bias correction along last axis.
// x: (32, 256, 8192) fp32  ->  out same shape.
// y[t] = 0.99*y[t-1] + 0.01*x[t], y[-1]=0 ; out[t] = y[t] / (1 - 0.99^(t+1))
//
// One 256-thread block per row (8192 rows).
//   stage-in : global_load_lds width-16 DMA, source index pre-swizzled
//              (LDS dest lane-linear as HW requires; LDS holds sw4 layout)
//   scan     : 8 x ds_read_b128 (swizzled addr, 2-way banks = free) +
//              32-elem sequential register scan
//   carry    : Kogge-Stone shuffle scan (constexpr decay powers) +
//              cross-wave combine via separate 4-float LDS array
//   epilogue : bias-correct (rcp only for wave 0 -- exact, corr==1.0f for
//              t>=2048), 8 x ds_write_b128 back to LDS
//   stage-out: 8 x ds_read_b128 (swizzled) + coalesced float4 global stores
//              (round 1's direct 128B-strided stores cost 8x the L2 write
//              transactions per instruction: +12 us. Reverted.)

namespace {

constexpr int T = 8192;
constexpr int BLOCK = 256;
constexpr int CHUNK = T / BLOCK;    // 32 elements per thread
constexpr int NWAVE = BLOCK / 64;   // 4
constexpr int V4 = T / 4;           // 2048 float4 slots in LDS
constexpr int VPT = V4 / BLOCK;     // 8 float4 per thread

// XOR swizzle at float4 granularity: slot bits [2:0] ^= bits [5:3].
// Involution; never leaves the slot's 8-slot (128 B) period, so the
// DMA's wave-level destination window is unchanged. Every LDS access
// pattern below is 2-way per bank per 16-lane phase = conflict-free.
__device__ __forceinline__ int sw4(int v) { return v ^ ((v >> 3) & 7); }

__global__ __launch_bounds__(BLOCK, 4) void ema_kernel(const float* __restrict__ x,
                                                       float* __restrict__ out) {
  __shared__ float4 sm4[V4];     // 32 KiB
  __shared__ float smW[NWAVE];   // +16 B -> 4 blocks/CU (16 waves), plenty

  const int tid = threadIdx.x;
  const long long base = (long long)blockIdx.x * (long long)T;

  // ---- stage in: coalesced DMA, global source pre-swizzled ----
  const float4* xv = reinterpret_cast<const float4*>(x + base);
#pragma unroll
  for (int k = 0; k < VPT; ++k) {
    const int slot = tid + BLOCK * k;   // lane-linear LDS dest (HW requirement)
    const int g = sw4(slot);            // swizzle applied to the SOURCE
    __builtin_amdgcn_global_load_lds(
        (const __attribute__((address_space(1))) void*)(xv + g),
        (__attribute__((address_space(3))) void*)(sm4 + slot), 16, 0, 0);
  }
  __syncthreads();   // compiler emits the vmcnt(0) drain before s_barrier

  constexpr float A1 = 0.99f, M = 0.01f;
  constexpr float A2 = A1 * A1;
  constexpr float A4 = A2 * A2;
  constexpr float A8 = A4 * A4;
  constexpr float A16 = A8 * A8;
  constexpr float A32 = A16 * A16;       // decay across one CHUNK
  constexpr float A64 = A32 * A32;
  constexpr float A128 = A64 * A64;
  constexpr float A256 = A128 * A128;
  constexpr float A512 = A256 * A256;
  constexpr float A1024 = A512 * A512;
  constexpr float A2048 = A1024 * A1024; // decay across one wave (64 chunks)

  // ---- per-thread sequential scan of its contiguous chunk ----
  const int vbase = tid * VPT;
  float acc[CHUNK];
  float run = 0.0f;
#pragma unroll
  for (int e4 = 0; e4 < VPT; ++e4) {
    const float4 v = sm4[sw4(vbase + e4)];   // ds_read_b128, conflict-free
    run = fmaf(run, A1, M * v.x); acc[4 * e4 + 0] = run;
    run = fmaf(run, A1, M * v.y); acc[4 * e4 + 1] = run;
    run = fmaf(run, A1, M * v.z); acc[4 * e4 + 2] = run;
    run = fmaf(run, A1, M * v.w); acc[4 * e4 + 3] = run;
  }

  const int lane = tid & 63;
  const int w = tid >> 6;

  // ---- Kogge-Stone inclusive scan of chunk-finals across the wave ----
  float S = run;
  {
    float t;
    t = __shfl_up(S, 1, 64);  if (lane >= 1)  S = fmaf(t, A32,   S);
    t = __shfl_up(S, 2, 64);  if (lane >= 2)  S = fmaf(t, A64,   S);
    t = __shfl_up(S, 4, 64);  if (lane >= 4)  S = fmaf(t, A128,  S);
    t = __shfl_up(S, 8, 64);  if (lane >= 8)  S = fmaf(t, A256,  S);
    t = __shfl_up(S, 16, 64); if (lane >= 16) S = fmaf(t, A512,  S);
    t = __shfl_up(S, 32, 64); if (lane >= 32) S = fmaf(t, A1024, S);
  }
  if (lane == 63) smW[w] = S;        // wave total W_w
  const float Sprev = __shfl_up(S, 1, 64);
  __syncthreads();

  // Q_w = sum_{v<w} A2048^(w-1-v) * W_v
  float Q = 0.0f;
#pragma unroll
  for (int v = 0; v < NWAVE - 1; ++v) {
    if (v < w) Q = fmaf(Q, A2048, smW[v]);
  }

  // Dlane = A32^lane (exact binary decomposition, no transcendentals)
  float Dlane = 1.0f;
  if (lane & 1)  Dlane *= A32;
  if (lane & 2)  Dlane *= A64;
  if (lane & 4)  Dlane *= A128;
  if (lane & 8)  Dlane *= A256;
  if (lane & 16) Dlane *= A512;
  if (lane & 32) Dlane *= A1024;

  // carry = y[cbase - 1]
  const float carry = (lane ? Sprev : 0.0f) + Dlane * Q;

  // ---- epilogue: bias-correct, write back to LDS as float4 ----
  float pw = 1.0f;

  if (w == 0) {
    // t < 2048: real correction. Pt = 0.99^(32*tid), tid < 64.
    float Pt = 1.0f;
    if (tid & 1)  Pt *= A32;
    if (tid & 2)  Pt *= A64;
    if (tid & 4)  Pt *= A128;
    if (tid & 8)  Pt *= A256;
    if (tid & 16) Pt *= A512;
    if (tid & 32) Pt *= A1024;
#pragma unroll
    for (int e4 = 0; e4 < VPT; ++e4) {
      float4 o;
      pw *= A1; Pt *= A1;
      o.x = fmaf(carry, pw, acc[4 * e4 + 0]) * __builtin_amdgcn_rcpf(1.0f - Pt);
      pw *= A1; Pt *= A1;
      o.y = fmaf(carry, pw, acc[4 * e4 + 1]) * __builtin_amdgcn_rcpf(1.0f - Pt);
      pw *= A1; Pt *= A1;
      o.z = fmaf(carry, pw, acc[4 * e4 + 2]) * __builtin_amdgcn_rcpf(1.0f - Pt);
      pw *= A1; Pt *= A1;
      o.w = fmaf(carry, pw, acc[4 * e4 + 3]) * __builtin_amdgcn_rcpf(1.0f - Pt);
      sm4[sw4(vbase + e4)] = o;            // ds_write_b128, conflict-free
    }
  } else {
    // t >= 2048: Pt <= 0.99^2049 ~ 1.1e-9 < 2^-25, so 1-Pt == 1.0f and
    // corr == 1.0f exactly -- identical to the rcp path, without the rcp.
#pragma unroll
    for (int e4 = 0; e4 < VPT; ++e4) {
      float4 o;
      pw *= A1; o.x = fmaf(carry, pw, acc[4 * e4 + 0]);
      pw *= A1; o.y = fmaf(carry, pw, acc[4 * e4 + 1]);
      pw *= A1; o.z = fmaf(carry, pw, acc[4 * e4 + 2]);
      pw *= A1; o.w = fmaf(carry, pw, acc[4 * e4 + 3]);
      sm4[sw4(vbase + e4)] = o;            // ds_write_b128, conflict-free
    }
  }
  __syncthreads();

  // ---- stage out: swizzled ds_read_b128, coalesced float4 stores ----
  float4* ov = reinterpret_cast<float4*>(out + base);
#pragma unroll
  for (int k = 0; k < VPT; ++k) {
    const int u = tid + BLOCK * k;
    ov[u] = sm4[sw4(u)];                   // 8 lines/instruction at L2
  }
}

}  // namespace

extern "C" void kernel_launch(void* const* d_in, const int* in_sizes, int n_in,
                              void* d_out, int out_size, void* d_ws, size_t ws_size,
                              hipStream_t stream) {
  const float* x = (const float*)d_in[0];
  float* out = (float*)d_out;
  const int rows = in_sizes[0] / T;  // 32*256 = 8192
  ema_kernel<<<dim3(rows), dim3(BLOCK), 0, stream>>>(x, out);
}

// Round 3
// 429.485 us; speedup vs baseline: 1.0282x; 1.0081x over previous
//
#include <hip/hip_runtime.h>

// EMA with bias correction along last axis.
// x: (32, 256, 8192) fp32  ->  out same shape.
// y[t] = 0.99*y[t-1] + 0.01*x[t], y[-1]=0 ; out[t] = y[t] / (1 - 0.99^(t+1))
//
// ROW PER WAVE, ZERO BARRIERS. 256-thread block = 4 waves = 4 independent
// rows; grid 2048. Each wave streams its row in 8 segments of 1024 floats
// through a private double-buffered 4 KiB LDS pair:
//   seg loop: ds_read_b128 frags (waits only on THIS seg's DMA; prefetch
//             for s+1 is issued AFTER, so it is never drained) ->
//             16-elem register scan -> 6-step Kogge-Stone (A16 powers) ->
//             carry + bias-correct (rcp only for t<2048, exact) ->
//             restage through same buffer -> coalesced float4 stores.
// Intra-wave DS ordering is program-order (lockstep wave), so the
// read->write->read buffer reuse needs no sync. Segment carry crosses via
// __shfl(S,63). LDS 32 KiB/block -> 5 blocks/CU = 20 independent waves/CU.

namespace {

constexpr int T = 8192;
constexpr int BLOCK = 256;
constexpr int WPB = BLOCK / 64;       // 4 waves per block, one row each
constexpr int SEGV = 256;             // float4 slots per segment (1024 floats)
constexpr int NSEG = T / (4 * SEGV);  // 8 segments per row

// XOR swizzle at float4 granularity within an 8-slot (128 B) period.
// Involution. Both access patterns below (slot=4*lane+e and slot=lane+64k)
// land exactly 2 lanes per bank-quad per 16-lane phase = conflict-free.
__device__ __forceinline__ int sw4(int s) { return s ^ ((s >> 3) & 7); }

__device__ __forceinline__ void dma16(const float4* g, float4* l) {
  __builtin_amdgcn_global_load_lds(
      (const __attribute__((address_space(1))) void*)g,
      (__attribute__((address_space(3))) void*)l, 16, 0, 0);
}

__global__ __launch_bounds__(BLOCK, 5) void ema_kernel(const float* __restrict__ x,
                                                       float* __restrict__ out) {
  __shared__ float4 sm4[WPB][2][SEGV];  // 32 KiB/block -> 5 blocks/CU

  const int tid = threadIdx.x;
  const int lane = tid & 63;
  const int w = tid >> 6;
  const long long row = (long long)blockIdx.x * WPB + w;
  const float4* xv = reinterpret_cast<const float4*>(x) + row * (T / 4);
  float4* ov = reinterpret_cast<float4*>(out) + row * (T / 4);

  constexpr float A1 = 0.99f, M = 0.01f;
  constexpr float A2 = A1 * A1;
  constexpr float A4 = A2 * A2;
  constexpr float A8 = A4 * A4;
  constexpr float A16 = A8 * A8;       // decay across one lane-chunk
  constexpr float A32 = A16 * A16;
  constexpr float A64 = A32 * A32;
  constexpr float A128 = A64 * A64;
  constexpr float A256 = A128 * A128;
  constexpr float A512 = A256 * A256;
  constexpr float A1024 = A512 * A512; // decay across one segment

  // Dlane = A^(16*lane), exact binary decomposition
  float Dlane = 1.0f;
  if (lane & 1)  Dlane *= A16;
  if (lane & 2)  Dlane *= A32;
  if (lane & 4)  Dlane *= A64;
  if (lane & 8)  Dlane *= A128;
  if (lane & 16) Dlane *= A256;
  if (lane & 32) Dlane *= A512;

  // ---- prologue: DMA segment 0 (source pre-swizzled, LDS dest linear) ----
#pragma unroll
  for (int k = 0; k < 4; ++k) {
    const int slot = lane + 64 * k;
    dma16(xv + sw4(slot), &sm4[w][0][slot]);
  }

  float c_in = 0.0f;

#pragma unroll
  for (int s = 0; s < NSEG; ++s) {
    const int b = s & 1;

    // ---- scan-input fragments: waits only on DMA(s) ----
    const float4 f0 = sm4[w][b][sw4(4 * lane + 0)];
    const float4 f1 = sm4[w][b][sw4(4 * lane + 1)];
    const float4 f2 = sm4[w][b][sw4(4 * lane + 2)];
    const float4 f3 = sm4[w][b][sw4(4 * lane + 3)];

    // ---- prefetch next segment into the other buffer ----
    if (s + 1 < NSEG) {
#pragma unroll
      for (int k = 0; k < 4; ++k) {
        const int slot = lane + 64 * k;
        dma16(xv + (s + 1) * SEGV + sw4(slot), &sm4[w][b ^ 1][slot]);
      }
    }

    // ---- per-lane sequential scan of 16 contiguous elements ----
    float acc[16];
    float run = 0.0f;
    run = fmaf(run, A1, M * f0.x); acc[0]  = run;
    run = fmaf(run, A1, M * f0.y); acc[1]  = run;
    run = fmaf(run, A1, M * f0.z); acc[2]  = run;
    run = fmaf(run, A1, M * f0.w); acc[3]  = run;
    run = fmaf(run, A1, M * f1.x); acc[4]  = run;
    run = fmaf(run, A1, M * f1.y); acc[5]  = run;
    run = fmaf(run, A1, M * f1.z); acc[6]  = run;
    run = fmaf(run, A1, M * f1.w); acc[7]  = run;
    run = fmaf(run, A1, M * f2.x); acc[8]  = run;
    run = fmaf(run, A1, M * f2.y); acc[9]  = run;
    run = fmaf(run, A1, M * f2.z); acc[10] = run;
    run = fmaf(run, A1, M * f2.w); acc[11] = run;
    run = fmaf(run, A1, M * f3.x); acc[12] = run;
    run = fmaf(run, A1, M * f3.y); acc[13] = run;
    run = fmaf(run, A1, M * f3.z); acc[14] = run;
    run = fmaf(run, A1, M * f3.w); acc[15] = run;

    // ---- Kogge-Stone inclusive scan of chunk-finals across the wave ----
    float S = run;
    {
      float t;
      t = __shfl_up(S, 1, 64);  if (lane >= 1)  S = fmaf(t, A16,  S);
      t = __shfl_up(S, 2, 64);  if (lane >= 2)  S = fmaf(t, A32,  S);
      t = __shfl_up(S, 4, 64);  if (lane >= 4)  S = fmaf(t, A64,  S);
      t = __shfl_up(S, 8, 64);  if (lane >= 8)  S = fmaf(t, A128, S);
      t = __shfl_up(S, 16, 64); if (lane >= 16) S = fmaf(t, A256, S);
      t = __shfl_up(S, 32, 64); if (lane >= 32) S = fmaf(t, A512, S);
    }
    const float Sprev = __shfl_up(S, 1, 64);

    // carry = y just before this lane's chunk; c_in = y just before segment
    const float carry = (lane ? Sprev : 0.0f) + Dlane * c_in;
    c_in = __shfl(S, 63, 64) + A1024 * c_in;   // segment total, uniform

    // ---- epilogue: add carry, bias-correct ----
    float4 y0, y1, y2, y3;
    float pw = 1.0f;
    if (s < 2) {
      // t < 2048: real correction. Pt = A^(s*1024 + 16*lane), then *A1/elem.
      float Pt = (s == 1) ? Dlane * A1024 : Dlane;
      pw *= A1; Pt *= A1; y0.x = fmaf(carry, pw, acc[0])  * __builtin_amdgcn_rcpf(1.0f - Pt);
      pw *= A1; Pt *= A1; y0.y = fmaf(carry, pw, acc[1])  * __builtin_amdgcn_rcpf(1.0f - Pt);
      pw *= A1; Pt *= A1; y0.z = fmaf(carry, pw, acc[2])  * __builtin_amdgcn_rcpf(1.0f - Pt);
      pw *= A1; Pt *= A1; y0.w = fmaf(carry, pw, acc[3])  * __builtin_amdgcn_rcpf(1.0f - Pt);
      pw *= A1; Pt *= A1; y1.x = fmaf(carry, pw, acc[4])  * __builtin_amdgcn_rcpf(1.0f - Pt);
      pw *= A1; Pt *= A1; y1.y = fmaf(carry, pw, acc[5])  * __builtin_amdgcn_rcpf(1.0f - Pt);
      pw *= A1; Pt *= A1; y1.z = fmaf(carry, pw, acc[6])  * __builtin_amdgcn_rcpf(1.0f - Pt);
      pw *= A1; Pt *= A1; y1.w = fmaf(carry, pw, acc[7])  * __builtin_amdgcn_rcpf(1.0f - Pt);
      pw *= A1; Pt *= A1; y2.x = fmaf(carry, pw, acc[8])  * __builtin_amdgcn_rcpf(1.0f - Pt);
      pw *= A1; Pt *= A1; y2.y = fmaf(carry, pw, acc[9])  * __builtin_amdgcn_rcpf(1.0f - Pt);
      pw *= A1; Pt *= A1; y2.z = fmaf(carry, pw, acc[10]) * __builtin_amdgcn_rcpf(1.0f - Pt);
      pw *= A1; Pt *= A1; y2.w = fmaf(carry, pw, acc[11]) * __builtin_amdgcn_rcpf(1.0f - Pt);
      pw *= A1; Pt *= A1; y3.x = fmaf(carry, pw, acc[12]) * __builtin_amdgcn_rcpf(1.0f - Pt);
      pw *= A1; Pt *= A1; y3.y = fmaf(carry, pw, acc[13]) * __builtin_amdgcn_rcpf(1.0f - Pt);
      pw *= A1; Pt *= A1; y3.z = fmaf(carry, pw, acc[14]) * __builtin_amdgcn_rcpf(1.0f - Pt);
      pw *= A1; Pt *= A1; y3.w = fmaf(carry, pw, acc[15]) * __builtin_amdgcn_rcpf(1.0f - Pt);
    } else {
      // t >= 2048: A^(t+1) < 2^-25 so 1-Pt == 1.0f, corr == 1.0f exactly.
      pw *= A1; y0.x = fmaf(carry, pw, acc[0]);
      pw *= A1; y0.y = fmaf(carry, pw, acc[1]);
      pw *= A1; y0.z = fmaf(carry, pw, acc[2]);
      pw *= A1; y0.w = fmaf(carry, pw, acc[3]);
      pw *= A1; y1.x = fmaf(carry, pw, acc[4]);
      pw *= A1; y1.y = fmaf(carry, pw, acc[5]);
      pw *= A1; y1.z = fmaf(carry, pw, acc[6]);
      pw *= A1; y1.w = fmaf(carry, pw, acc[7]);
      pw *= A1; y2.x = fmaf(carry, pw, acc[8]);
      pw *= A1; y2.y = fmaf(carry, pw, acc[9]);
      pw *= A1; y2.z = fmaf(carry, pw, acc[10]);
      pw *= A1; y2.w = fmaf(carry, pw, acc[11]);
      pw *= A1; y3.x = fmaf(carry, pw, acc[12]);
      pw *= A1; y3.y = fmaf(carry, pw, acc[13]);
      pw *= A1; y3.z = fmaf(carry, pw, acc[14]);
      pw *= A1; y3.w = fmaf(carry, pw, acc[15]);
    }

    // ---- restage through the same buffer (intra-wave, in-order DS pipe:
    //      all scan reads precede these writes in program order) ----
    sm4[w][b][sw4(4 * lane + 0)] = y0;
    sm4[w][b][sw4(4 * lane + 1)] = y1;
    sm4[w][b][sw4(4 * lane + 2)] = y2;
    sm4[w][b][sw4(4 * lane + 3)] = y3;

    // ---- coalesced float4 stores ----
#pragma unroll
    for (int k = 0; k < 4; ++k) {
      const int u = lane + 64 * k;
      ov[s * SEGV + u] = sm4[w][b][sw4(u)];
    }
  }
}

}  // namespace

extern "C" void kernel_launch(void* const* d_in, const int* in_sizes, int n_in,
                              void* d_out, int out_size, void* d_ws, size_t ws_size,
                              hipStream_t stream) {
  const float* x = (const float*)d_in[0];
  float* out = (float*)d_out;
  const int rows = in_sizes[0] / T;       // 8192
  ema_kernel<<<dim3(rows / WPB), dim3(BLOCK), 0, stream>>>(x, out);
}